// Round 1
// 586.010 us; speedup vs baseline: 1.0507x; 1.0507x over previous
//
#include <hip/hip_runtime.h>
#include <hip/hip_bf16.h>
#include <math.h>

#define B_  4
#define N_  4096
#define D_  1024
#define H_  16
#define DK_ 64
#define M_  256
#define R_  (B_*N_)          // 16384 rows
#define EPS_ 1e-6f
#define VTROWS_ 80           // 64 V rows + row64=ones(ksum) + 65..79 pad
#define KVROWS_ 128          // KVb bf16: 64 KV + 64=ksum_hi + 65=ksum_lo + 0-pad
#define PHK_PAD 136          // fused_kv  Phi LDS [m][136]
#define PHQ_PAD 264          // fused_ctx Phi LDS [n][264]

typedef __bf16 bf16;
typedef __bf16 bf16x4 __attribute__((ext_vector_type(4)));
typedef __bf16 bf16x8 __attribute__((ext_vector_type(8)));
typedef _Float16 f16;
typedef _Float16 f16x4 __attribute__((ext_vector_type(4)));
typedef _Float16 f16x8 __attribute__((ext_vector_type(8)));
typedef float  f32x4  __attribute__((ext_vector_type(4)));

#define GLD(gp, lp) __builtin_amdgcn_global_load_lds( \
    (const __attribute__((address_space(1))) void*)(gp), \
    (__attribute__((address_space(3))) void*)(lp), 16, 0, 0)

// ---------------------------------------------------------------------------
// prep kernels
// ---------------------------------------------------------------------------
__global__ __launch_bounds__(256)
void split_f16v(const float* __restrict__ in, f16* __restrict__ hi,
                f16* __restrict__ lo, int n4)
{
    int i = blockIdx.x * 256 + threadIdx.x;
    if (i < n4) {
        float4 v = ((const float4*)in)[i];
        f16x4 h = { (f16)v.x, (f16)v.y, (f16)v.z, (f16)v.w };
        ((f16x4*)hi)[i] = h;
        if (lo) {
            f16x4 l = { (f16)(v.x - (float)h[0]), (f16)(v.y - (float)h[1]),
                        (f16)(v.z - (float)h[2]), (f16)(v.w - (float)h[3]) };
            ((f16x4*)lo)[i] = l;
        }
    }
}

__global__ __launch_bounds__(256)
void f32_to_bf16v(const float* __restrict__ in, bf16* __restrict__ o, int n4)
{
    int i = blockIdx.x * 256 + threadIdx.x;
    if (i < n4) {
        float4 v = ((const float4*)in)[i];
        bf16x4 h = { (bf16)v.x, (bf16)v.y, (bf16)v.z, (bf16)v.w };
        ((bf16x4*)o)[i] = h;
    }
}

__global__ __launch_bounds__(256)
void zero_f32(float* __restrict__ p, int n)
{
    int i = blockIdx.x * 256 + threadIdx.x;
    if (i < n) p[i] = 0.f;
}

__global__ __launch_bounds__(256)
void init_vt(bf16* __restrict__ VT)
{
    int i = blockIdx.x * 256 + threadIdx.x;          // 64bh x 16rows x 4096
    if (i >= B_*H_*16*N_) return;
    int bh  = i >> 16;
    int rem = i & 65535;
    int row = 64 + (rem >> 12);
    int n   = rem & (N_-1);
    VT[((size_t)bh*VTROWS_ + row)*N_ + n] = (row == 64) ? (bf16)1.0f : (bf16)0.0f;
}

__global__ __launch_bounds__(256)
void pack_kv(const float* __restrict__ KVt32, bf16* __restrict__ KVb)
{
    int i = blockIdx.x * 256 + threadIdx.x;          // 64bh x 128 x 256
    if (i >= B_*H_*KVROWS_*M_) return;
    int bh  = i >> 15;
    int rem = i & 32767;
    int row = rem >> 8;
    int m   = rem & (M_-1);
    bf16 o = (bf16)0.0f;
    if (row < 64) {
        o = (bf16)KVt32[((size_t)bh*VTROWS_ + row)*M_ + m];
    } else if (row == 64) {
        o = (bf16)KVt32[((size_t)bh*VTROWS_ + 64)*M_ + m];
    } else if (row == 65) {
        float v = KVt32[((size_t)bh*VTROWS_ + 64)*M_ + m];
        o = (bf16)(v - (float)(bf16)v);
    }
    KVb[i] = o;
}

// ---------------------------------------------------------------------------
// Unified QKV projection — 256x256 tile, BK=64, 8 waves (2Mx4N), 8-phase
// counted-vmcnt schedule (T1+T2+T3+T4+T5 per the 8-phase template).
//
// LDS: sA/sB double-buffered K-tiles (256x64 f16 = 32 KB each) = 128 KB.
// Swizzle: 16B chunks within each 1024B line permuted by seg ^= (row&7)
//   (involution). Applied on the global SOURCE address of global_load_lds
//   (dest stays lane-linear, as HW requires) and on the ds_read byte addr.
//   Result: the 16 m16-lanes of each ds_read_b128 land on 8 distinct bank
//   groups (2-way aliasing = free) instead of 16-way same-bank.
//
// Phase schedule per iteration (computes K-tiles t0=2it from P0, t1 from P1,
// stages one 128x64 half-tile per phase; 1 region is only overwritten in a
// phase strictly after its last ds_read; vmcnt(4)+barrier at ph4/ph8
// guarantees landing before first read):
//   ph1: rdA(P0,rows0-3)+rdB(P0,cols0-1), stage P1.Ah0(t1),  MFMA Q00
//   ph2: rdB(P0,cols2-3),                 stage P1.Ah1(t1),  MFMA Q01
//   ph3: rdA(P0,rows4-7),                 stage P0.Bh0(t2),  MFMA Q11
//   ph4: (regs only)                      stage P0.Bh1(t2),  vmcnt(4), MFMA Q10
//   ph5-8: same on P1/t1, staging P0.Ah0/Ah1(t2), P1.Bh0/Bh1(t3), vmcnt(4)@ph8
// ---------------------------------------------------------------------------

#define STAGE_(dstbuf, srcp, kt, half) do { \
    _Pragma("unroll") \
    for (int q_ = 0; q_ < 2; ++q_) { \
        int idx_ = q_*512 + tid; \
        int row_ = idx_ >> 3; \
        int seg_ = (idx_ & 7) ^ (row_ & 7); \
        GLD((srcp) + (size_t)((half)*128 + row_) * D_ + (kt)*64 + seg_*8, \
            &(dstbuf)[(half)*8192 + idx_*8]); \
    } } while (0)

#define LDA_(buf, i0) do { \
    _Pragma("unroll") \
    for (int i_ = 0; i_ < 4; ++i_) { \
        _Pragma("unroll") \
        for (int k_ = 0; k_ < 2; ++k_) { \
            int row_ = warp_m*128 + ((i0)+i_)*16 + m16; \
            int off_ = (row_*128 + k_*64 + quad*16) ^ ((row_ & 7) << 4); \
            a[i_][k_] = *(const f16x8*)((const char*)(buf) + off_); \
        } } } while (0)

#define LDB_(buf, j0) do { \
    _Pragma("unroll") \
    for (int j_ = 0; j_ < 2; ++j_) { \
        _Pragma("unroll") \
        for (int k_ = 0; k_ < 2; ++k_) { \
            int row_ = warp_n*64 + ((j0)+j_)*16 + m16; \
            int off_ = (row_*128 + k_*64 + quad*16) ^ ((row_ & 7) << 4); \
            b[(j0)+j_][k_] = *(const f16x8*)((const char*)(buf) + off_); \
        } } } while (0)

#define MFMA_Q(I0, J0) do { \
    _Pragma("unroll") \
    for (int i_ = 0; i_ < 4; ++i_) { \
        _Pragma("unroll") \
        for (int j_ = 0; j_ < 2; ++j_) { \
            _Pragma("unroll") \
            for (int k_ = 0; k_ < 2; ++k_) \
                acc[(I0)+i_][(J0)+j_] = __builtin_amdgcn_mfma_f32_16x16x32_f16( \
                    a[i_][k_], b[(J0)+j_][k_], acc[(I0)+i_][(J0)+j_], 0, 0, 0); \
        } } } while (0)

#define BAR_()  asm volatile("s_barrier" ::: "memory")
#define LGK0_() asm volatile("s_waitcnt lgkmcnt(0)" ::: "memory")
#define VMC4_() asm volatile("s_waitcnt vmcnt(4)" ::: "memory")
#define PRIO1_() __builtin_amdgcn_s_setprio(1)
#define PRIO0_() __builtin_amdgcn_s_setprio(0)

__global__ __launch_bounds__(512, 2)
void gemm_qkv(const f16* __restrict__ X, const f16* __restrict__ Wh,
              const float* __restrict__ bqkv,
              f16* __restrict__ Qh, f16* __restrict__ Kh, bf16* __restrict__ VT)
{
    __shared__ __align__(16) f16 sA[2][256*64];   // 64 KB
    __shared__ __align__(16) f16 sB[2][256*64];   // 64 KB
    const int tid = threadIdx.x;

    // T1: bijective XCD swizzle (nwg = 12*64 = 768, 768 % 8 == 0)
    const int nwg  = gridDim.x * gridDim.y;
    int flat = blockIdx.y * gridDim.x + blockIdx.x;
    int wgid = (flat & 7) * (nwg >> 3) + (flat >> 3);
    const int bm = (wgid / 12) * 256;
    const int bn = (wgid % 12) * 256;

    const int lane = tid & 63, wave = tid >> 6;
    const int warp_m = wave >> 2, warp_n = wave & 3;   // 2 x 4 waves
    const int m16 = lane & 15, quad = lane >> 4;

    const f16* gA = X  + (size_t)bm * D_;
    const f16* gB = Wh + (size_t)bn * D_;

    f32x4 acc[8][4];
    #pragma unroll
    for (int i = 0; i < 8; ++i)
        #pragma unroll
        for (int j = 0; j < 4; ++j)
            acc[i][j] = (f32x4){0.f, 0.f, 0.f, 0.f};

    f16x8 a[4][2], b[4][2];

    // prologue: tile0 A+B -> P0, tile1 B -> P1 (12 loads); vmcnt(4) leaves
    // only P1.B possibly outstanding -> P0 fully landed before ph1 reads.
    STAGE_(sA[0], gA, 0, 0);
    STAGE_(sA[0], gA, 0, 1);
    STAGE_(sB[0], gB, 0, 0);
    STAGE_(sB[0], gB, 0, 1);
    STAGE_(sB[1], gB, 1, 0);
    STAGE_(sB[1], gB, 1, 1);
    VMC4_();
    BAR_();

    for (int it = 0; it < 8; ++it) {
        const int t1 = 2*it + 1, t2 = 2*it + 2, t3 = 2*it + 3;
        // ---------- K-tile t0 from P0 ----------
        LDA_(sA[0], 0); LDB_(sB[0], 0);
        STAGE_(sA[1], gA, t1, 0);
        BAR_(); LGK0_();
        PRIO1_(); MFMA_Q(0, 0); PRIO0_();
        BAR_();

        LDB_(sB[0], 2);
        STAGE_(sA[1], gA, t1, 1);
        BAR_(); LGK0_();
        PRIO1_(); MFMA_Q(0, 2); PRIO0_();
        BAR_();

        LDA_(sA[0], 4);
        if (t2 < 16) STAGE_(sB[0], gB, t2, 0);
        BAR_(); LGK0_();
        PRIO1_(); MFMA_Q(4, 2); PRIO0_();
        BAR_();

        if (t2 < 16) STAGE_(sB[0], gB, t2, 1);
        VMC4_();
        BAR_();
        PRIO1_(); MFMA_Q(4, 0); PRIO0_();
        BAR_();

        // ---------- K-tile t1 from P1 ----------
        LDA_(sA[1], 0); LDB_(sB[1], 0);
        if (t2 < 16) STAGE_(sA[0], gA, t2, 0);
        BAR_(); LGK0_();
        PRIO1_(); MFMA_Q(0, 0); PRIO0_();
        BAR_();

        LDB_(sB[1], 2);
        if (t2 < 16) STAGE_(sA[0], gA, t2, 1);
        BAR_(); LGK0_();
        PRIO1_(); MFMA_Q(0, 2); PRIO0_();
        BAR_();

        LDA_(sA[1], 4);
        if (t3 < 16) STAGE_(sB[1], gB, t3, 0);
        BAR_(); LGK0_();
        PRIO1_(); MFMA_Q(4, 2); PRIO0_();
        BAR_();

        if (t3 < 16) STAGE_(sB[1], gB, t3, 1);
        VMC4_();
        BAR_();
        PRIO1_(); MFMA_Q(4, 0); PRIO0_();
        BAR_();
    }

    // epilogue: scatter Q / K / V (+bias). 256-col tiles never straddle the
    // Q/K/V boundaries (1024 % 256 == 0).
    #pragma unroll
    for (int j = 0; j < 4; ++j) {
        int gcol = bn + warp_n*64 + j*16 + m16;
        float bv = bqkv[gcol];
        #pragma unroll
        for (int i = 0; i < 8; ++i) {
            int row0 = bm + warp_m*128 + i*16 + quad*4;
            if (gcol >= 2*D_) {
                int vcol = gcol - 2*D_;
                int hh = vcol >> 6, dd = vcol & 63;
                int bb = row0 >> 12, nn = row0 & (N_-1);
                bf16x4 pk = { (bf16)(acc[i][j][0]+bv), (bf16)(acc[i][j][1]+bv),
                              (bf16)(acc[i][j][2]+bv), (bf16)(acc[i][j][3]+bv) };
                *(bf16x4*)&VT[(((size_t)bb*H_+hh)*VTROWS_ + dd)*N_ + nn] = pk;
            } else if (gcol >= D_) {
                #pragma unroll
                for (int r = 0; r < 4; ++r)
                    Kh[(size_t)(row0+r) * D_ + gcol - D_] = (f16)(acc[i][j][r] + bv);
            } else {
                #pragma unroll
                for (int r = 0; r < 4; ++r)
                    Qh[(size_t)(row0+r) * D_ + gcol] = (f16)(acc[i][j][r] + bv);
            }
        }
    }
}

// ---------------------------------------------------------------------------
// fused_kv: per (b,h, n-slab of 1024): for each 128-key sub-tile:
//   feat (fp16 MFMA, omega hi/lo) -> rowmax -> exp -> Phi bf16 into LDS [m][n]
//   then KVt[d][m] += sum_n VT[d][n]*Phi[m][n] via MFMA vs LDS VT slab.
// ---------------------------------------------------------------------------
__global__ __launch_bounds__(256)
void fused_kv(const f16* __restrict__ Kh, const bf16* __restrict__ VT,
              const f16* __restrict__ omhi, const f16* __restrict__ omlo,
              const int* __restrict__ mask, float* __restrict__ KVt32)
{
    __shared__ f16  sK[128*64];          // 16 KB
    __shared__ bf16 sVT[VTROWS_*128];    // 20 KB
    __shared__ bf16 sPhi[M_*PHK_PAD];    // 68 KB  [m][n] pad 136
    __shared__ int  sMask[128];
    const int nsp = blockIdx.x;          // 0..3
    const int h = blockIdx.y, b = blockIdx.z;
    const int bh = b*H_ + h;
    const int tid = threadIdx.x, lane = tid & 63, wave = tid >> 6;
    const int m16 = lane & 15, quad = lane >> 4;
    const int wm = wave * 64;            // wave's m-range for kv MFMA
    const float inv_sqrt_m = rsqrtf((float)M_ + 1e-6f);
    const f16* omh = omhi + (size_t)h * M_ * DK_;
    const f16* oml = omlo + (size_t)h * M_ * DK_;

    f32x4 kvacc[5][4];
    #pragma unroll
    for (int d = 0; d < 5; ++d)
        #pragma unroll
        for (int j = 0; j < 4; ++j)
            kvacc[d][j] = (f32x4){0.f, 0.f, 0.f, 0.f};

    for (int sub = 0; sub < 8; ++sub) {
        const int n0 = nsp*1024 + sub*128;
        __syncthreads();   // prior iter's readers of sK/sVT/sMask are done
        #pragma unroll
        for (int it = 0; it < 4; ++it) {   // K slab 128x64 f16
            int idx = it*256 + tid;
            int row = idx >> 3, seg = idx & 7;
            GLD(Kh + (size_t)(b*N_ + n0 + row) * D_ + h*DK_ + seg*8, &sK[idx*8]);
        }
        #pragma unroll
        for (int it = 0; it < 5; ++it) {   // VT slab 80x128 bf16 (1280 segs)
            int idx = it*256 + tid;
            int row = idx >> 4, seg = idx & 15;
            GLD(VT + ((size_t)bh*VTROWS_ + row)*N_ + n0 + seg*8, &sVT[idx*8]);
        }
        if (tid < 128) sMask[tid] = mask[b*N_ + n0 + tid];
        __syncthreads();

        // ---- feat: proj = K . omega^T (wave owns 32 n-rows) ----
        f16x8 ah[2][2];
        #pragma unroll
        for (int i = 0; i < 2; ++i)
            #pragma unroll
            for (int k = 0; k < 2; ++k)
                ah[i][k] = *(const f16x8*)&sK[(wave*32 + i*16 + m16)*64 + k*32 + quad*8];

        f32x4 acc[2][16];
        #pragma unroll
        for (int i = 0; i < 2; ++i)
            #pragma unroll
            for (int j = 0; j < 16; ++j)
                acc[i][j] = (f32x4){0.f, 0.f, 0.f, 0.f};

        #pragma unroll
        for (int j = 0; j < 16; ++j) {
            size_t ro = (size_t)(j*16 + m16) * DK_ + quad*8;
            f16x8 bh0 = *(const f16x8*)&omh[ro];
            f16x8 bh1 = *(const f16x8*)&omh[ro + 32];
            f16x8 bl0 = *(const f16x8*)&oml[ro];
            f16x8 bl1 = *(const f16x8*)&oml[ro + 32];
            #pragma unroll
            for (int i = 0; i < 2; ++i) {
                acc[i][j] = __builtin_amdgcn_mfma_f32_16x16x32_f16(ah[i][0], bh0, acc[i][j], 0,0,0);
                acc[i][j] = __builtin_amdgcn_mfma_f32_16x16x32_f16(ah[i][0], bl0, acc[i][j], 0,0,0);
                acc[i][j] = __builtin_amdgcn_mfma_f32_16x16x32_f16(ah[i][1], bh1, acc[i][j], 0,0,0);
                acc[i][j] = __builtin_amdgcn_mfma_f32_16x16x32_f16(ah[i][1], bl1, acc[i][j], 0,0,0);
            }
        }
        // rowmax + exp
        #pragma unroll
        for (int i = 0; i < 2; ++i)
            #pragma unroll
            for (int r = 0; r < 4; ++r) {
                float mx = acc[i][0][r];
                #pragma unroll
                for (int j = 1; j < 16; ++j) mx = fmaxf(mx, acc[i][j][r]);
                mx = fmaxf(mx, __shfl_xor(mx, 1, 64));
                mx = fmaxf(mx, __shfl_xor(mx, 2, 64));
                mx = fmaxf(mx, __shfl_xor(mx, 4, 64));
                mx = fmaxf(mx, __shfl_xor(mx, 8, 64));
                #pragma unroll
                for (int j = 0; j < 16; ++j)
                    acc[i][j][r] = __expf(acc[i][j][r] - mx) * inv_sqrt_m;
            }
        // Phi -> LDS [m][n] padded, PAD keys zeroed (bf16x4 along n)
        #pragma unroll
        for (int i = 0; i < 2; ++i) {
            int nloc = wave*32 + i*16 + quad*4;
            #pragma unroll
            for (int j = 0; j < 16; ++j) {
                bf16x4 pk;
                #pragma unroll
                for (int r = 0; r < 4; ++r)
                    pk[r] = sMask[nloc + r] ? (bf16)0.0f : (bf16)acc[i][j][r];
                *(bf16x4*)&sPhi[(j*16 + m16)*PHK_PAD + nloc] = pk;
            }
        }
        __syncthreads();

        // ---- kv MFMA: KVt[d][m] += sum_n VT[d][n] * Phi[m][n] ----
        #pragma unroll
        for (int kk = 0; kk < 128; kk += 32) {
            bf16x8 av[5], bp[4];
            #pragma unroll
            for (int d = 0; d < 5; ++d)
                av[d] = *(const bf16x8*)&sVT[(d*16 + m16)*128 + kk + quad*8];
            #pragma unroll
            for (int j = 0; j < 4; ++j)
                bp[j] = *(const bf16x8*)&sPhi[(wm + j*16 + m16)*PHK_PAD + kk + quad*8];
            #pragma unroll
            for (int d = 0; d < 5; ++d)
                #pragma unroll
                for (int j = 0; j < 4; ++j)
                    kvacc[d][j] = __builtin_amdgcn_mfma_f32_16x16x32_bf16(
                        av[d], bp[j], kvacc[d][j], 0, 0, 0);
        }
    }

    #pragma unroll
    for (int d = 0; d < 5; ++d)
        #pragma unroll
        for (int j = 0; j < 4; ++j) {
            int drow = d*16 + quad*4;
            int m = wm + j*16 + m16;
            #pragma unroll
            for (int r = 0; r < 4; ++r)
                atomicAdd(&KVt32[((size_t)bh*VTROWS_ + drow + r)*M_ + m],
                          kvacc[d][j][r]);
        }
}

// ---------------------------------------------------------------------------
// fused_ctx: per (b,h, 128 q-rows): feat -> exp -> Phi bf16 into LDS [n][m]
// (padded 264), then ctx = (Phi @ KVb^T)/den with KVb staged per k0.
// ---------------------------------------------------------------------------
__global__ __launch_bounds__(256)
void fused_ctx(const f16* __restrict__ Qh, const f16* __restrict__ omhi,
               const f16* __restrict__ omlo, const bf16* __restrict__ KVb,
               bf16* __restrict__ ctx)
{
    __shared__ f16  sQ[128*64];          // 16 KB
    __shared__ bf16 sW[128*64];          // 16 KB
    __shared__ bf16 sPhi[128*PHQ_PAD];   // 67.6 KB [n][m] pad 264
    __shared__ float sden[2][128];
    const int nblk = blockIdx.x, h = blockIdx.y, b = blockIdx.z;
    const int bh = b*H_ + h;
    const int tid = threadIdx.x, lane = tid & 63, wave = tid >> 6;
    const int m16 = lane & 15, quad = lane >> 4;
    const float inv_sqrt_m = rsqrtf((float)M_ + 1e-6f);
    const f16* omh = omhi + (size_t)h * M_ * DK_;
    const f16* oml = omlo + (size_t)h * M_ * DK_;

    #pragma unroll
    for (int it = 0; it < 4; ++it) {     // Q slab 128x64 f16
        int idx = it*256 + tid;
        int row = idx >> 3, seg = idx & 7;
        GLD(Qh + (size_t)(b*N_ + nblk*128 + row) * D_ + h*DK_ + seg*8, &sQ[idx*8]);
    }
    __syncthreads();

    // ---- feat (wave owns 32 n-rows) ----
    {
        f16x8 ah[2][2];
        #pragma unroll
        for (int i = 0; i < 2; ++i)
            #pragma unroll
            for (int k = 0; k < 2; ++k)
                ah[i][k] = *(const f16x8*)&sQ[(wave*32 + i*16 + m16)*64 + k*32 + quad*8];

        f32x4 acc[2][16];
        #pragma unroll
        for (int i = 0; i < 2; ++i)
            #pragma unroll
            for (int j = 0; j < 16; ++j)
                acc[i][j] = (f32x4){0.f, 0.f, 0.f, 0.f};

        #pragma unroll
        for (int j = 0; j < 16; ++j) {
            size_t ro = (size_t)(j*16 + m16) * DK_ + quad*8;
            f16x8 bh0 = *(const f16x8*)&omh[ro];
            f16x8 bh1 = *(const f16x8*)&omh[ro + 32];
            f16x8 bl0 = *(const f16x8*)&oml[ro];
            f16x8 bl1 = *(const f16x8*)&oml[ro + 32];
            #pragma unroll
            for (int i = 0; i < 2; ++i) {
                acc[i][j] = __builtin_amdgcn_mfma_f32_16x16x32_f16(ah[i][0], bh0, acc[i][j], 0,0,0);
                acc[i][j] = __builtin_amdgcn_mfma_f32_16x16x32_f16(ah[i][0], bl0, acc[i][j], 0,0,0);
                acc[i][j] = __builtin_amdgcn_mfma_f32_16x16x32_f16(ah[i][1], bh1, acc[i][j], 0,0,0);
                acc[i][j] = __builtin_amdgcn_mfma_f32_16x16x32_f16(ah[i][1], bl1, acc[i][j], 0,0,0);
            }
        }
        #pragma unroll
        for (int i = 0; i < 2; ++i)
            #pragma unroll
            for (int r = 0; r < 4; ++r) {
                float mx = acc[i][0][r];
                #pragma unroll
                for (int j = 1; j < 16; ++j) mx = fmaxf(mx, acc[i][j][r]);
                mx = fmaxf(mx, __shfl_xor(mx, 1, 64));
                mx = fmaxf(mx, __shfl_xor(mx, 2, 64));
                mx = fmaxf(mx, __shfl_xor(mx, 4, 64));
                mx = fmaxf(mx, __shfl_xor(mx, 8, 64));
                #pragma unroll
                for (int j = 0; j < 16; ++j)
                    acc[i][j][r] = __expf(acc[i][j][r] - mx) * inv_sqrt_m;
            }
        // Phi -> LDS [n][m] padded (scalar b16; pad kills write conflicts)
        #pragma unroll
        for (int i = 0; i < 2; ++i) {
            int nloc0 = wave*32 + i*16 + quad*4;
            #pragma unroll
            for (int j = 0; j < 16; ++j)
                #pragma unroll
                for (int r = 0; r < 4; ++r)
                    sPhi[(nloc0 + r)*PHQ_PAD + j*16 + m16] = (bf16)acc[i][j][r];
        }
    }
    __syncthreads();   // Phi visible; sQ reads done (sW is separate anyway)

    // ---- ctx GEMM: A = Phi (LDS), W = KVb (staged per k0) ----
    const int wm = (wave & 1) * 64, wn = (wave >> 1) * 64;
    f32x4 cacc[4][4];
    #pragma unroll
    for (int i = 0; i < 4; ++i)
        #pragma unroll
        for (int j = 0; j < 4; ++j)
            cacc[i][j] = (f32x4){0.f, 0.f, 0.f, 0.f};

    for (int k0 = 0; k0 < M_; k0 += 64) {
        __syncthreads();
        #pragma unroll
        for (int it = 0; it < 4; ++it) {
            int idx = it*256 + tid;
            int row = idx >> 3, seg = idx & 7;
            GLD(KVb + ((size_t)bh*KVROWS_ + row)*M_ + k0 + seg*8, &sW[idx*8]);
        }
        __syncthreads();
        #pragma unroll
        for (int kk = 0; kk < 64; kk += 32) {
            bf16x8 af[4], wf[4];
            #pragma unroll
            for (int i = 0; i < 4; ++i)
                af[i] = *(const bf16x8*)&sPhi[(wm + i*16 + m16)*PHQ_PAD + k0 + kk + quad*8];
            #pragma unroll
            for (int j = 0; j < 4; ++j)
                wf[j] = *(const bf16x8*)&sW[(wn + j*16 + m16)*64 + kk + quad*8];
            #pragma unroll
            for (int i = 0; i < 4; ++i)
                #pragma unroll
                for (int j = 0; j < 4; ++j)
                    cacc[i][j] = __builtin_amdgcn_mfma_f32_16x16x32_bf16(
                        af[i], wf[j], cacc[i][j], 0, 0, 0);
        }
    }

    if (wn == 64 && m16 < 2) {
        #pragma unroll
        for (int i = 0; i < 4; ++i)
            #pragma unroll
            for (int r = 0; r < 4; ++r)
                sden[m16][wm + i*16 + quad*4 + r] = cacc[i][0][r];
    }
    __syncthreads();
    if (wn == 0) {
        #pragma unroll
        for (int i = 0; i < 4; ++i) {
            int lrow0 = wm + i*16 + quad*4;
            #pragma unroll
            for (int r = 0; r < 4; ++r) {
                int lrow = lrow0 + r;
                int n = nblk*128 + lrow;
                float den = sden[0][lrow] + sden[1][lrow] + EPS_;
                #pragma unroll
                for (int j = 0; j < 4; ++j)
                    ctx[(size_t)(b*N_ + n)*D_ + h*DK_ + j*16 + m16] =
                        (bf16)(cacc[i][j][r] / den);
            }
        }
    }
}

// ---------------------------------------------------------------------------
// Output projection: out = mask ? 0 : ctx @ Wout^T + bout   (bf16 MFMA, fp32 out)
// ---------------------------------------------------------------------------
__global__ __launch_bounds__(256)
void gemm_out(const bf16* __restrict__ A, const bf16* __restrict__ W,
              const float* __restrict__ bias, float* __restrict__ C,
              const int* __restrict__ mask)
{
    __shared__ bf16 sA[128*64];
    __shared__ bf16 sB[128*64];
    const int tid  = threadIdx.x;
    const int bm   = blockIdx.y * 128;
    const int bn   = blockIdx.x * 128;
    const int lane = tid & 63, wave = tid >> 6;
    const int wm   = (wave & 1) * 64, wn = (wave >> 1) * 64;
    const int m16  = lane & 15, quad = lane >> 4;

    f32x4 acc[4][4];
    #pragma unroll
    for (int i = 0; i < 4; ++i)
        #pragma unroll
        for (int j = 0; j < 4; ++j)
            acc[i][j] = (f32x4){0.f, 0.f, 0.f, 0.f};

    for (int k0 = 0; k0 < D_; k0 += 64) {
        __syncthreads();
        #pragma unroll
        for (int it = 0; it < 4; ++it) {
            int idx = it*256 + tid;
            int row = idx >> 3, seg = idx & 7;
            GLD(A + (size_t)(bm + row) * D_ + k0 + seg*8, &sA[idx*8]);
            GLD(W + (size_t)(bn + row) * D_ + k0 + seg*8, &sB[idx*8]);
        }
        __syncthreads();
        #pragma unroll
        for (int kk = 0; kk < 64; kk += 32) {
            bf16x8 af[4], bfr[4];
            #pragma unroll
            for (int i = 0; i < 4; ++i)
                af[i] = *(const bf16x8*)&sA[(wm + i*16 + m16)*64 + kk + quad*8];
            #pragma unroll
            for (int j = 0; j < 4; ++j)
                bfr[j] = *(const bf16x8*)&sB[(wn + j*16 + m16)*64 + kk + quad*8];
            #pragma unroll
            for (int i = 0; i < 4; ++i)
                #pragma unroll
                for (int j = 0; j < 4; ++j)
                    acc[i][j] = __builtin_amdgcn_mfma_f32_16x16x32_bf16(
                        af[i], bfr[j], acc[i][j], 0, 0, 0);
        }
    }

    #pragma unroll
    for (int j = 0; j < 4; ++j) {
        int col = bn + wn + j*16 + m16;
        float bv = bias[col];
        #pragma unroll
        for (int i = 0; i < 4; ++i) {
            int row0 = bm + wm + i*16 + quad*4;
            #pragma unroll
            for (int r = 0; r < 4; ++r) {
                int row = row0 + r;
                float v = acc[i][j][r] + bv;
                if (mask[row] != 0) v = 0.0f;
                C[(size_t)row * D_ + col] = v;
            }
        }
    }
}

// ---------------------------------------------------------------------------
extern "C" void kernel_launch(void* const* d_in, const int* in_sizes, int n_in,
                              void* d_out, int out_size, void* d_ws, size_t ws_size,
                              hipStream_t stream)
{
    const float* x     = (const float*)d_in[0];
    const int*   mask  = (const int*)d_in[1];     // 1 = PAD
    const float* Wqkv  = (const float*)d_in[2];
    const float* bqkv  = (const float*)d_in[3];
    const float* Wout  = (const float*)d_in[4];
    const float* bout  = (const float*)d_in[5];
    const float* omega = (const float*)d_in[6];
    float* out = (float*)d_out;

    char* w = (char*)d_ws;
    f16*   Wh    = (f16*)w;    w += (size_t)3*D_*D_ * 2;              //   6.29 MB
    bf16*  Wob   = (bf16*)w;   w += (size_t)D_*D_ * 2;                //   2.10 MB
    f16*   omhi  = (f16*)w;    w += (size_t)H_*M_*DK_ * 2;            //   0.52 MB
    f16*   omlo  = (f16*)w;    w += (size_t)H_*M_*DK_ * 2;            //   0.52 MB
    f16*   xh    = (f16*)w;    w += (size_t)R_ * D_ * 2;              //  33.55 MB
    f16*   Qh    = (f16*)w;    w += (size_t)R_ * D_ * 2;              //  33.55 MB
    f16*   Kh    = (f16*)w;    w += (size_t)R_ * D_ * 2;              //  33.55 MB (-> ctx)
    bf16*  VT    = (bf16*)w;   w += (size_t)B_*H_*VTROWS_*N_ * 2;     //  41.94 MB
    float* KVt32 = (float*)w;  w += (size_t)B_*H_*VTROWS_*M_ * 4;     //   5.24 MB
    bf16*  KVb   = (bf16*)w;   w += (size_t)B_*H_*KVROWS_*M_ * 2;     //   4.19 MB
    bf16*  VC    = (bf16*)Kh;                                         // alias (Kh dead after fused_kv)

    // 0) prep
    split_f16v<<<(R_*D_/4 + 255)/256, 256, 0, stream>>>(x, xh, nullptr, R_*D_/4);
    split_f16v<<<(3*D_*D_/4 + 255)/256, 256, 0, stream>>>(Wqkv, Wh, nullptr, 3*D_*D_/4);
    split_f16v<<<(H_*M_*DK_/4 + 255)/256, 256, 0, stream>>>(omega, omhi, omlo, H_*M_*DK_/4);
    f32_to_bf16v<<<(D_*D_/4 + 255)/256, 256, 0, stream>>>(Wout, Wob, D_*D_/4);
    zero_f32<<<(B_*H_*VTROWS_*M_ + 255)/256, 256, 0, stream>>>(KVt32, B_*H_*VTROWS_*M_);
    init_vt<<<(B_*H_*16*N_ + 255)/256, 256, 0, stream>>>(VT);

    // 1) unified QKV projection (fp16, 256^2 8-phase): Qh, Kh fp16; V -> VT bf16
    gemm_qkv<<<dim3(3*D_/256, R_/256), 512, 0, stream>>>(xh, Wh, bqkv, Qh, Kh, VT);

    // 2) fused K-features + KV/ksum accumulation (Phi_K in LDS only)
    fused_kv<<<dim3(4, H_, B_), 256, 0, stream>>>(Kh, VT, omhi, omlo, mask, KVt32);

    // 3) pack KVt32 -> KVb bf16 (ksum hi/lo rows 64/65, zero pad to 128)
    pack_kv<<<(B_*H_*KVROWS_*M_ + 255)/256, 256, 0, stream>>>(KVt32, KVb);

    // 4) fused Q-features + ctx (Phi_Q in LDS only) -> VC bf16 (aliases Kh)
    fused_ctx<<<dim3(N_/128, H_, B_), 256, 0, stream>>>(Qh, omhi, omlo, KVb, VC);

    // 5) output projection + bias + PAD-query zeroing -> fp32 out
    gemm_out<<<dim3(8, R_/128), 256, 0, stream>>>(VC, Wob, bout, out, mask);
}